// Round 7
// baseline (131.596 us; speedup 1.0000x reference)
//
#include <hip/hip_runtime.h>
#include <math.h>

// Lorenz Lyapunov-exponent integrator — round 7.
// R6 post-mortem: scalar codegen bloated to ~191 VALU inst/step/traj vs f2's
// measured-perfect 77 (VALU-cycles from rocprof). Suspects: SLP vectorizer
// repacking scalars (insert/extract churn) and/or launch_bounds(256,4)
// pressure-mode scheduling/remat (VGPR squeezed to 36).
// R7 = the clean-scalar experiment: 1 traj/thread (4 waves/SIMD, the TLP
// that gave R1 its 90% issue), NO launch_bounds min-waves, NO struct, NO
// helper functions — flat body, T==100 specialized to 5 blocks of 20
// fully-unrolled steps + GS. All fp expression trees textually identical
// to R4-R6 (absmax stable at 0.502 across those rounds).
// Issue floor: 77 inst * 2 cyc * 4 waves * 100 steps = 61.6k cyc = 25.7 us.

#define SIGMA 10.0f
#define RHO   28.0f
#define DT    0.01f
#define BETA  (8.0f / 3.0f)
#define LN2_HALF 0.34657359027997264f   // 0.5 * ln(2)
#define GS_K 20

#pragma clang fp contract(fast)

// One RK4 + tangent-map + Q-update step, operating on the enclosing scope's
// X,Y,Z,q?? locals. Textually identical arithmetic to R4-R6.
#define RK4_JQ_STEP()                                                         \
  {                                                                           \
    float k1x = SIGMA * (Y - X);                                              \
    float k1y = X * (RHO - Z) - Y;                                            \
    float k1z = X * Y - BETA * Z;                                             \
    float ax = X + (DT * 0.5f) * k1x;                                         \
    float ay = Y + (DT * 0.5f) * k1y;                                         \
    float az = Z + (DT * 0.5f) * k1z;                                         \
    float k2x = SIGMA * (ay - ax);                                            \
    float k2y = ax * (RHO - az) - ay;                                         \
    float k2z = ax * ay - BETA * az;                                          \
    float bx = X + (DT * 0.5f) * k2x;                                         \
    float by = Y + (DT * 0.5f) * k2y;                                         \
    float bz = Z + (DT * 0.5f) * k2z;                                         \
    float k3x = SIGMA * (by - bx);                                            \
    float k3y = bx * (RHO - bz) - by;                                         \
    float k3z = bx * by - BETA * bz;                                          \
    float cx = X + DT * k2x;  /* (sic) k2 — reference quirk */                \
    float cy = Y + DT * k2y;                                                  \
    float cz = Z + DT * k2z;                                                  \
    float k4x = SIGMA * (cy - cx);                                            \
    float k4y = cx * (RHO - cz) - cy;                                         \
    float k4z = cx * cy - BETA * cz;                                          \
    X = X + DT * (k1x + 2.0f * k2x + 2.0f * k3x + k4x) * (1.0f / 6.0f);       \
    Y = Y + DT * (k1y + 2.0f * k2y + 2.0f * k3y + k4y) * (1.0f / 6.0f);       \
    Z = Z + DT * (k1z + 2.0f * k2z + 2.0f * k3z + k4z) * (1.0f / 6.0f);       \
    const float j10 = DT * (RHO - Z);                                         \
    const float j12 = -DT * X;                                                \
    const float j20 = DT * Y;                                                 \
    const float j21 = DT * X;                                                 \
    const float j00 = 1.0f - DT * SIGMA;                                      \
    const float j01 = DT * SIGMA;                                             \
    const float j11 = 1.0f - DT;                                              \
    const float j22 = 1.0f - DT * BETA;                                       \
    float n00 = j00 * q00 + j01 * q10;                                        \
    float n01 = j00 * q01 + j01 * q11;                                        \
    float n02 = j00 * q02 + j01 * q12;                                        \
    float n10 = j10 * q00 + j11 * q10 + j12 * q20;                            \
    float n11 = j10 * q01 + j11 * q11 + j12 * q21;                            \
    float n12 = j10 * q02 + j11 * q12 + j12 * q22;                            \
    float n20 = j20 * q00 + j21 * q10 + j22 * q20;                            \
    float n21 = j20 * q01 + j21 * q11 + j22 * q21;                            \
    float n22 = j20 * q02 + j21 * q12 + j22 * q22;                            \
    q00 = n00; q01 = n01; q02 = n02;                                          \
    q10 = n10; q11 = n11; q12 = n12;                                          \
    q20 = n20; q21 = n21; q22 = n22;                                          \
  }

// Classical GS, unnormalized, projection coeffs from ORIGINAL columns.
#define GRAM_SCHMIDT()                                                        \
  {                                                                           \
    float ib0 = q00 * q00 + q10 * q10 + q20 * q20;                            \
    float rib0 = __builtin_amdgcn_rcpf(ib0);                                  \
    float d01 = q00 * q01 + q10 * q11 + q20 * q21;                            \
    float c1 = d01 * rib0;                                                    \
    float b10 = q01 - c1 * q00;                                               \
    float b11 = q11 - c1 * q10;                                               \
    float b12 = q21 - c1 * q20;                                               \
    float d02 = q00 * q02 + q10 * q12 + q20 * q22;                            \
    float c2 = d02 * rib0;                                                    \
    float e0 = q02 - c2 * q00;                                                \
    float e1 = q12 - c2 * q10;                                                \
    float e2 = q22 - c2 * q20;                                                \
    float ib1 = b10 * b10 + b11 * b11 + b12 * b12;                            \
    float d12 = b10 * q02 + b11 * q12 + b12 * q22;                            \
    float c3 = d12 * __builtin_amdgcn_rcpf(ib1);                              \
    q02 = e0 - c3 * b10;                                                      \
    q12 = e1 - c3 * b11;                                                      \
    q22 = e2 - c3 * b12;                                                      \
    q01 = b10; q11 = b11; q21 = b12;                                          \
  }

__global__ void lorenz_lya_kernel(const float* __restrict__ x0,
                                  const float* __restrict__ ts,
                                  float* __restrict__ out,
                                  int B, int T) {
    int b = blockIdx.x * blockDim.x + threadIdx.x;
    if (b >= B) return;

    float X = x0[0 * B + b];
    float Y = x0[1 * B + b];
    float Z = x0[2 * B + b];

    float q00 = 1.0f, q01 = 0.0f, q02 = 0.0f;
    float q10 = 0.0f, q11 = 1.0f, q12 = 0.0f;
    float q20 = 0.0f, q21 = 0.0f, q22 = 1.0f;

    float t_last = ts[T - 1];

    if (T == 100) {
        // Specialized: 5 blocks of 20 steps, GS after each block.
        #pragma unroll 1
        for (int blk = 0; blk < 5; ++blk) {
            #pragma unroll 4
            for (int u = 0; u < GS_K; ++u) {
                RK4_JQ_STEP();
            }
            GRAM_SCHMIDT();
        }
    } else {
        int it = 0;
        while (it < T) {
            int kend = T - it;
            int n = (kend >= GS_K) ? GS_K : kend;
            for (int u = 0; u < n; ++u) {
                RK4_JQ_STEP();
            }
            it += n;
            GRAM_SCHMIDT();
        }
    }

    // Final column norms^2; lya_j = 0.5*ln2*log2(ib_j) / (t_last + DT)
    float ib0 = q00 * q00 + q10 * q10 + q20 * q20;
    float ib1 = q01 * q01 + q11 * q11 + q21 * q21;
    float ib2 = q02 * q02 + q12 * q12 + q22 * q22;

    float scale = LN2_HALF * __builtin_amdgcn_rcpf(t_last + DT);
    out[0 * B + b] = __builtin_amdgcn_logf(ib0) * scale;
    out[1 * B + b] = __builtin_amdgcn_logf(ib1) * scale;
    out[2 * B + b] = __builtin_amdgcn_logf(ib2) * scale;
    out[3 * B + b] = X;
    out[4 * B + b] = Y;
    out[5 * B + b] = Z;
}

extern "C" void kernel_launch(void* const* d_in, const int* in_sizes, int n_in,
                              void* d_out, int out_size, void* d_ws, size_t ws_size,
                              hipStream_t stream) {
    const float* x0 = (const float*)d_in[0];
    const float* ts = (const float*)d_in[1];
    float* out = (float*)d_out;
    int B = in_sizes[0] / 3;
    int T = in_sizes[1];
    int threads = 256;
    int blocks = (B + threads - 1) / threads;
    lorenz_lya_kernel<<<blocks, threads, 0, stream>>>(x0, ts, out, B, T);
}

// Round 8
// 116.084 us; speedup vs baseline: 1.1336x; 1.1336x over previous
//
#include <hip/hip_runtime.h>
#include <math.h>

// Lorenz Lyapunov-exponent integrator — round 8.
// Cycle accounting across R1..R7: useful VALU work is ~616 busy-cyc/SIMD/step
// in every config; f2 codegen achieves exactly that (R5: 61.5k cyc total),
// scalar codegen emits 2.5-3x (R6: 153k, R7: 183k busy cyc) — SLP vectorizer
// packing one trajectory's components into v_pk_fma_f32 with insert/extract
// shuffle churn. f2/f4 are clean but cap TLP at 2/1 waves/SIMD (63-66% issue);
// 4 waves/SIMD reached 90% (R1).
// R8: scalar 1 traj/thread (4 waves/SIMD) + empty inline-asm register fences
// on pack-candidate temporaries — zero emitted instructions, but opaque to
// SLP, forcing clean scalar v_fma_f32. Fences sit between statements so each
// statement's fma-contraction tree is unchanged (absmax stability).
// Floor: 77 inst * 2 cyc * 4 waves * 100 steps = 61.6k cyc = 25.7 us.

#define SIGMA 10.0f
#define RHO   28.0f
#define DT    0.01f
#define BETA  (8.0f / 3.0f)
#define LN2_HALF 0.34657359027997264f   // 0.5 * ln(2)
#define GS_K 20

#pragma clang fp contract(fast)

// Empty asm: pins the value in a VGPR, emits nothing, blocks SLP packing.
#define FENCE(v) asm volatile("" : "+v"(v))

// One RK4 + tangent-map + Q-update step on enclosing-scope X,Y,Z,q??.
// Arithmetic trees textually identical to R4-R7.
#define RK4_JQ_STEP()                                                         \
  {                                                                           \
    float k1x = SIGMA * (Y - X);                                              \
    float k1y = X * (RHO - Z) - Y;                                            \
    float k1z = X * Y - BETA * Z;                                             \
    FENCE(k1x); FENCE(k1y); FENCE(k1z);                                       \
    float ax = X + (DT * 0.5f) * k1x;                                         \
    float ay = Y + (DT * 0.5f) * k1y;                                         \
    float az = Z + (DT * 0.5f) * k1z;                                         \
    FENCE(ax); FENCE(ay); FENCE(az);                                          \
    float k2x = SIGMA * (ay - ax);                                            \
    float k2y = ax * (RHO - az) - ay;                                         \
    float k2z = ax * ay - BETA * az;                                          \
    FENCE(k2x); FENCE(k2y); FENCE(k2z);                                       \
    float bx = X + (DT * 0.5f) * k2x;                                         \
    float by = Y + (DT * 0.5f) * k2y;                                         \
    float bz = Z + (DT * 0.5f) * k2z;                                         \
    FENCE(bx); FENCE(by); FENCE(bz);                                          \
    float k3x = SIGMA * (by - bx);                                            \
    float k3y = bx * (RHO - bz) - by;                                         \
    float k3z = bx * by - BETA * bz;                                          \
    FENCE(k3x); FENCE(k3y); FENCE(k3z);                                       \
    float cx = X + DT * k2x;  /* (sic) k2 — reference quirk */                \
    float cy = Y + DT * k2y;                                                  \
    float cz = Z + DT * k2z;                                                  \
    FENCE(cx); FENCE(cy); FENCE(cz);                                          \
    float k4x = SIGMA * (cy - cx);                                            \
    float k4y = cx * (RHO - cz) - cy;                                         \
    float k4z = cx * cy - BETA * cz;                                          \
    FENCE(k4x); FENCE(k4y); FENCE(k4z);                                       \
    X = X + DT * (k1x + 2.0f * k2x + 2.0f * k3x + k4x) * (1.0f / 6.0f);       \
    Y = Y + DT * (k1y + 2.0f * k2y + 2.0f * k3y + k4y) * (1.0f / 6.0f);       \
    Z = Z + DT * (k1z + 2.0f * k2z + 2.0f * k3z + k4z) * (1.0f / 6.0f);       \
    FENCE(X); FENCE(Y); FENCE(Z);                                             \
    const float j10 = DT * (RHO - Z);                                         \
    const float j12 = -DT * X;                                                \
    const float j20 = DT * Y;                                                 \
    const float j21 = DT * X;                                                 \
    const float j00 = 1.0f - DT * SIGMA;                                      \
    const float j01 = DT * SIGMA;                                             \
    const float j11 = 1.0f - DT;                                              \
    const float j22 = 1.0f - DT * BETA;                                       \
    float n00 = j00 * q00 + j01 * q10;                                        \
    float n01 = j00 * q01 + j01 * q11;                                        \
    float n02 = j00 * q02 + j01 * q12;                                        \
    FENCE(n00); FENCE(n01); FENCE(n02);                                       \
    float n10 = j10 * q00 + j11 * q10 + j12 * q20;                            \
    float n11 = j10 * q01 + j11 * q11 + j12 * q21;                            \
    float n12 = j10 * q02 + j11 * q12 + j12 * q22;                            \
    FENCE(n10); FENCE(n11); FENCE(n12);                                       \
    float n20 = j20 * q00 + j21 * q10 + j22 * q20;                            \
    float n21 = j20 * q01 + j21 * q11 + j22 * q21;                            \
    float n22 = j20 * q02 + j21 * q12 + j22 * q22;                            \
    FENCE(n20); FENCE(n21); FENCE(n22);                                       \
    q00 = n00; q01 = n01; q02 = n02;                                          \
    q10 = n10; q11 = n11; q12 = n12;                                          \
    q20 = n20; q21 = n21; q22 = n22;                                          \
  }

// Classical GS, unnormalized, projection coeffs from ORIGINAL columns.
// Runs 5x total — no fences needed (churn here is amortized away).
#define GRAM_SCHMIDT()                                                        \
  {                                                                           \
    float ib0 = q00 * q00 + q10 * q10 + q20 * q20;                            \
    float rib0 = __builtin_amdgcn_rcpf(ib0);                                  \
    float d01 = q00 * q01 + q10 * q11 + q20 * q21;                            \
    float c1 = d01 * rib0;                                                    \
    float b10 = q01 - c1 * q00;                                               \
    float b11 = q11 - c1 * q10;                                               \
    float b12 = q21 - c1 * q20;                                               \
    float d02 = q00 * q02 + q10 * q12 + q20 * q22;                            \
    float c2 = d02 * rib0;                                                    \
    float e0 = q02 - c2 * q00;                                                \
    float e1 = q12 - c2 * q10;                                                \
    float e2 = q22 - c2 * q20;                                                \
    float ib1 = b10 * b10 + b11 * b11 + b12 * b12;                            \
    float d12 = b10 * q02 + b11 * q12 + b12 * q22;                            \
    float c3 = d12 * __builtin_amdgcn_rcpf(ib1);                              \
    q02 = e0 - c3 * b10;                                                      \
    q12 = e1 - c3 * b11;                                                      \
    q22 = e2 - c3 * b12;                                                      \
    q01 = b10; q11 = b11; q21 = b12;                                          \
  }

__global__ __launch_bounds__(256, 4)
void lorenz_lya_kernel(const float* __restrict__ x0,
                       const float* __restrict__ ts,
                       float* __restrict__ out,
                       int B, int T) {
    int b = blockIdx.x * blockDim.x + threadIdx.x;
    if (b >= B) return;

    float X = x0[0 * B + b];
    float Y = x0[1 * B + b];
    float Z = x0[2 * B + b];

    float q00 = 1.0f, q01 = 0.0f, q02 = 0.0f;
    float q10 = 0.0f, q11 = 1.0f, q12 = 0.0f;
    float q20 = 0.0f, q21 = 0.0f, q22 = 1.0f;

    float t_last = ts[T - 1];

    int it = 0;
    while (it < T) {
        int kend = T - it;
        int n = (kend >= GS_K) ? GS_K : kend;
        #pragma unroll 5
        for (int u = 0; u < n; ++u) {
            RK4_JQ_STEP();
        }
        it += n;
        GRAM_SCHMIDT();
    }

    // Final column norms^2; lya_j = 0.5*ln2*log2(ib_j) / (t_last + DT)
    float ib0 = q00 * q00 + q10 * q10 + q20 * q20;
    float ib1 = q01 * q01 + q11 * q11 + q21 * q21;
    float ib2 = q02 * q02 + q12 * q12 + q22 * q22;

    float scale = LN2_HALF * __builtin_amdgcn_rcpf(t_last + DT);
    out[0 * B + b] = __builtin_amdgcn_logf(ib0) * scale;
    out[1 * B + b] = __builtin_amdgcn_logf(ib1) * scale;
    out[2 * B + b] = __builtin_amdgcn_logf(ib2) * scale;
    out[3 * B + b] = X;
    out[4 * B + b] = Y;
    out[5 * B + b] = Z;
}

extern "C" void kernel_launch(void* const* d_in, const int* in_sizes, int n_in,
                              void* d_out, int out_size, void* d_ws, size_t ws_size,
                              hipStream_t stream) {
    const float* x0 = (const float*)d_in[0];
    const float* ts = (const float*)d_in[1];
    float* out = (float*)d_out;
    int B = in_sizes[0] / 3;
    int T = in_sizes[1];
    int threads = 256;
    int blocks = (B + threads - 1) / threads;
    lorenz_lya_kernel<<<blocks, threads, 0, stream>>>(x0, ts, out, B, T);
}

// Round 9
// 93.932 us; speedup vs baseline: 1.4010x; 1.2358x over previous
//
#include <hip/hip_runtime.h>
#include <math.h>

// Lorenz Lyapunov-exponent integrator — round 9.
// R8 post-mortem: source-level fences did NOT stop the scalar bloat
// (busy-cyc/SIMD 154k, same as R6's 153k vs the 61.6k ideal) — SLP packs
// defs and churns v_movs regardless. R5's f2 codegen is cycle-exact
// (61.5k busy = 77 pk x 4cyc x 2 waves x 100) but capped at 2 waves/SIMD
// where dependent-pk latency (~12cyc) > 2-wave issue round (8cyc) -> 63%.
// R9: take isel away from the compiler — the 77-op RK4+J+matmul step is
// written as per-op inline asm (v_sub/v_mul/v_fma_f32). Non-volatile asm:
// scheduler still reorders by dataflow; SLP cannot touch it. Scalar insts
// at 1 traj/thread = 4 waves/SIMD (the config that measured 88-91% busy).
// Trees hand-built to match R4-R6's contraction (absmax 0.502 band, away
// from R8's 0.871-vs-0.925 cliff).
// Floor: 77 x 2cyc x 4waves x 100 = 61.6k cyc/SIMD = 25.7 us; predict 28-30.

#define GS_K 20
#define LN2_HALF 0.34657359027997264f   // 0.5 * ln(2)

// Single-instruction asm helpers. Non-volatile: scheduled by dataflow,
// invisible to the SLP vectorizer. VOP3 (no literals) — constants arrive
// as loop-invariant VGPR inputs; 2.0 is a free inline constant.
#define VSUB(d, a, b)     asm("v_sub_f32 %0, %1, %2"      : "=v"(d) : "v"(a), "v"(b))
#define VADD(d, a, b)     asm("v_add_f32 %0, %1, %2"      : "=v"(d) : "v"(a), "v"(b))
#define VMUL(d, a, b)     asm("v_mul_f32 %0, %1, %2"      : "=v"(d) : "v"(a), "v"(b))
#define VFMA(d, a, b, c)  asm("v_fma_f32 %0, %1, %2, %3"  : "=v"(d) : "v"(a), "v"(b), "v"(c))
#define VFMAN(d, a, b, c) asm("v_fma_f32 %0, %1, %2, -%3" : "=v"(d) : "v"(a), "v"(b), "v"(c)) // a*b - c
#define VFMA2(d, b, c)    asm("v_fma_f32 %0, 2.0, %1, %2" : "=v"(d) : "v"(b), "v"(c))         // 2*b + c

__global__ __launch_bounds__(256, 4)
void lorenz_lya_kernel(const float* __restrict__ x0,
                       const float* __restrict__ ts,
                       float* __restrict__ out,
                       int B, int T) {
    int b = blockIdx.x * blockDim.x + threadIdx.x;
    if (b >= B) return;

    float X = x0[0 * B + b];
    float Y = x0[1 * B + b];
    float Z = x0[2 * B + b];

    float q00 = 1.0f, q01 = 0.0f, q02 = 0.0f;
    float q10 = 0.0f, q11 = 1.0f, q12 = 0.0f;
    float q20 = 0.0f, q21 = 0.0f, q22 = 1.0f;

    float t_last = ts[T - 1];

    // Loop-invariant constants (materialized once into VGPRs).
    const float cS   = 10.0f;                   // SIGMA
    const float cR   = 28.0f;                   // RHO
    const float cB   = 8.0f / 3.0f;             // BETA
    const float cDT  = 0.01f;
    const float cDT2 = 0.005f;                  // DT/2
    const float cNDT = -0.01f;
    const float c6   = 1.0f / 6.0f;
    const float cJ00 = 1.0f - 0.01f * 10.0f;    // 0.9
    const float cJ01 = 0.01f * 10.0f;           // 0.1
    const float cJ11 = 1.0f - 0.01f;            // 0.99
    const float cJ22 = 1.0f - 0.01f * (8.0f / 3.0f);

    int it = 0;
    while (it < T) {
        int kend = T - it;
        int n = (kend >= GS_K) ? GS_K : kend;
        #pragma unroll 1
        for (int u = 0; u < n; ++u) {
            float t0, t1, t2;
            float k1x, k1y, k1z, k2x, k2y, k2z, k3x, k3y, k3z, k4x, k4y, k4z;
            float ax, ay, az, bx, by, bz, cx, cy, cz;

            // ---- RK4 (reference quirk: k4 stage uses k2) ----
            VSUB(t0, Y, X);        VMUL(k1x, cS, t0);        // S*(Y-X)
            VSUB(t1, cR, Z);       VFMAN(k1y, X, t1, Y);     // X*(R-Z) - Y
            VMUL(t2, cB, Z);       VFMAN(k1z, X, Y, t2);     // X*Y - B*Z

            VFMA(ax, cDT2, k1x, X);
            VFMA(ay, cDT2, k1y, Y);
            VFMA(az, cDT2, k1z, Z);

            VSUB(t0, ay, ax);      VMUL(k2x, cS, t0);
            VSUB(t1, cR, az);      VFMAN(k2y, ax, t1, ay);
            VMUL(t2, cB, az);      VFMAN(k2z, ax, ay, t2);

            VFMA(bx, cDT2, k2x, X);
            VFMA(by, cDT2, k2y, Y);
            VFMA(bz, cDT2, k2z, Z);

            VSUB(t0, by, bx);      VMUL(k3x, cS, t0);
            VSUB(t1, cR, bz);      VFMAN(k3y, bx, t1, by);
            VMUL(t2, cB, bz);      VFMAN(k3z, bx, by, t2);

            VFMA(cx, cDT, k2x, X);   // (sic) k2
            VFMA(cy, cDT, k2y, Y);
            VFMA(cz, cDT, k2z, Z);

            VSUB(t0, cy, cx);      VMUL(k4x, cS, t0);
            VSUB(t1, cR, cz);      VFMAN(k4y, cx, t1, cy);
            VMUL(t2, cB, cz);      VFMAN(k4z, cx, cy, t2);

            // X += DT*(k1 + 2k2 + 2k3 + k4)/6
            VFMA2(t0, k2x, k1x);  VFMA2(t0, k3x, t0);  VADD(t0, t0, k4x);
            VMUL(t0, cDT, t0);    VFMA(X, t0, c6, X);
            VFMA2(t1, k2y, k1y);  VFMA2(t1, k3y, t1);  VADD(t1, t1, k4y);
            VMUL(t1, cDT, t1);    VFMA(Y, t1, c6, Y);
            VFMA2(t2, k2z, k1z);  VFMA2(t2, k3z, t2);  VADD(t2, t2, k4z);
            VMUL(t2, cDT, t2);    VFMA(Z, t2, c6, Z);

            // ---- Tangent map J = I + DT*Df at new x (j02 == 0) ----
            float j10, j12, j20, j21;
            VSUB(t0, cR, Z);   VMUL(j10, cDT, t0);
            VMUL(j12, cNDT, X);
            VMUL(j20, cDT, Y);
            VMUL(j21, cDT, X);

            // ---- Q = J @ Q ----
            float n00, n01, n02, n10, n11, n12, n20, n21, n22;
            VMUL(t0, cJ00, q00);  VFMA(n00, cJ01, q10, t0);
            VMUL(t0, cJ00, q01);  VFMA(n01, cJ01, q11, t0);
            VMUL(t0, cJ00, q02);  VFMA(n02, cJ01, q12, t0);
            VMUL(t0, j10, q00);   VFMA(t0, cJ11, q10, t0);  VFMA(n10, j12, q20, t0);
            VMUL(t1, j10, q01);   VFMA(t1, cJ11, q11, t1);  VFMA(n11, j12, q21, t1);
            VMUL(t2, j10, q02);   VFMA(t2, cJ11, q12, t2);  VFMA(n12, j12, q22, t2);
            VMUL(t0, j20, q00);   VFMA(t0, j21, q10, t0);   VFMA(n20, cJ22, q20, t0);
            VMUL(t1, j20, q01);   VFMA(t1, j21, q11, t1);   VFMA(n21, cJ22, q21, t1);
            VMUL(t2, j20, q02);   VFMA(t2, j21, q12, t2);   VFMA(n22, cJ22, q22, t2);

            q00 = n00; q01 = n01; q02 = n02;
            q10 = n10; q11 = n11; q12 = n12;
            q20 = n20; q21 = n21; q22 = n22;
        }
        it += n;

        // ---- Classical GS, unnormalized (coeffs from ORIGINAL columns).
        // Runs 5x total — plain C, bloat amortized to noise.
        {
            float ib0 = q00 * q00 + q10 * q10 + q20 * q20;
            float rib0 = __builtin_amdgcn_rcpf(ib0);
            float d01 = q00 * q01 + q10 * q11 + q20 * q21;
            float c1 = d01 * rib0;
            float b10 = q01 - c1 * q00;
            float b11 = q11 - c1 * q10;
            float b12 = q21 - c1 * q20;
            float d02 = q00 * q02 + q10 * q12 + q20 * q22;
            float c2 = d02 * rib0;
            float e0 = q02 - c2 * q00;
            float e1 = q12 - c2 * q10;
            float e2 = q22 - c2 * q20;
            float ib1 = b10 * b10 + b11 * b11 + b12 * b12;
            float d12 = b10 * q02 + b11 * q12 + b12 * q22;
            float c3 = d12 * __builtin_amdgcn_rcpf(ib1);
            q02 = e0 - c3 * b10;
            q12 = e1 - c3 * b11;
            q22 = e2 - c3 * b12;
            q01 = b10; q11 = b11; q21 = b12;
        }
    }

    // Final column norms^2; lya_j = 0.5*ln2*log2(ib_j) / (t_last + DT)
    float ib0 = q00 * q00 + q10 * q10 + q20 * q20;
    float ib1 = q01 * q01 + q11 * q11 + q21 * q21;
    float ib2 = q02 * q02 + q12 * q12 + q22 * q22;

    float scale = LN2_HALF * __builtin_amdgcn_rcpf(t_last + 0.01f);
    out[0 * B + b] = __builtin_amdgcn_logf(ib0) * scale;
    out[1 * B + b] = __builtin_amdgcn_logf(ib1) * scale;
    out[2 * B + b] = __builtin_amdgcn_logf(ib2) * scale;
    out[3 * B + b] = X;
    out[4 * B + b] = Y;
    out[5 * B + b] = Z;
}

extern "C" void kernel_launch(void* const* d_in, const int* in_sizes, int n_in,
                              void* d_out, int out_size, void* d_ws, size_t ws_size,
                              hipStream_t stream) {
    const float* x0 = (const float*)d_in[0];
    const float* ts = (const float*)d_in[1];
    float* out = (float*)d_out;
    int B = in_sizes[0] / 3;
    int T = in_sizes[1];
    int threads = 256;
    int blocks = (B + threads - 1) / threads;
    lorenz_lya_kernel<<<blocks, threads, 0, stream>>>(x0, ts, out, B, T);
}

// Round 10
// 91.307 us; speedup vs baseline: 1.4413x; 1.0287x over previous
//
#include <hip/hip_runtime.h>
#include <math.h>

// Lorenz Lyapunov-exponent integrator — round 10.
// R9 post-mortem: per-op asm blocks cost ~+40 v_mov/step from failed
// register coalescing across block seams (114k busy-cyc/SIMD vs 61.6k
// ideal; VALU busy but half the insts are copies). R10: the whole
// 77-instruction RK4+J+matmul step is ONE asm block — no seams, no movs.
// Matmul re-sequenced column-wise so results write directly into the q
// registers (reads-before-overwrite verified); fma trees bit-identical
// to R9 (absmax 0.5029 there). 1 traj/thread = 4 waves/SIMD; dependent
// latency ≤6cyc < 8-cyc 4-wave issue rotation -> ~full issue efficiency.
// Floor: 77 x 2cyc x 4waves x 100 steps = 61.6k cyc/SIMD = 25.7 us.
// Predict ~28 us kernel.

#define GS_K 20
#define LN2_HALF 0.34657359027997264f   // 0.5 * ln(2)

__global__ __launch_bounds__(256, 4)
void lorenz_lya_kernel(const float* __restrict__ x0,
                       const float* __restrict__ ts,
                       float* __restrict__ out,
                       int B, int T) {
    int b = blockIdx.x * blockDim.x + threadIdx.x;
    if (b >= B) return;

    float X = x0[0 * B + b];
    float Y = x0[1 * B + b];
    float Z = x0[2 * B + b];

    float q00 = 1.0f, q01 = 0.0f, q02 = 0.0f;
    float q10 = 0.0f, q11 = 1.0f, q12 = 0.0f;
    float q20 = 0.0f, q21 = 0.0f, q22 = 1.0f;

    float t_last = ts[T - 1];

    // Loop-invariant constants in VGPRs (VOP3 forbids literals; 2.0 is a
    // free inline constant used directly in the asm text).
    const float cS   = 10.0f;                    // SIGMA
    const float cR   = 28.0f;                    // RHO
    const float cB   = 8.0f / 3.0f;              // BETA
    const float cDT  = 0.01f;
    const float cDT2 = 0.005f;                   // DT/2
    const float c6   = 1.0f / 6.0f;
    const float cJ00 = 1.0f - 0.01f * 10.0f;     // 0.9
    const float cJ01 = 0.01f * 10.0f;            // 0.1
    const float cJ11 = 1.0f - 0.01f;             // 0.99
    const float cJ22 = 1.0f - 0.01f * (8.0f / 3.0f);

    int it = 0;
    while (it < T) {
        int kend = T - it;
        int n = (kend >= GS_K) ? GS_K : kend;
        #pragma unroll 1
        for (int u = 0; u < n; ++u) {
            float t0, t1, t2, sx, sy, sz;
            float k1x, k1y, k1z, k2x, k2y, k2z, k3x, k3y, k3z, k4x, k4y, k4z;
            // One asm block = the whole step. After RK4 combine, the k1/k2
            // registers are dead and are reused for the J entries:
            //   k1x := j10 = DT*(R-Z), k1y := j12 = -DT*X,
            //   k1z := j20 = DT*Y,     k2x := j21 = DT*X.
            asm(// ---- k1 = f(X,Y,Z) ----
                "v_sub_f32 %[t0], %[Y], %[X]\n\t"
                "v_mul_f32 %[k1x], %[cS], %[t0]\n\t"
                "v_sub_f32 %[t1], %[cR], %[Z]\n\t"
                "v_fma_f32 %[k1y], %[X], %[t1], -%[Y]\n\t"
                "v_mul_f32 %[t2], %[cB], %[Z]\n\t"
                "v_fma_f32 %[k1z], %[X], %[Y], -%[t2]\n\t"
                // ---- stage a = x + DT/2*k1 ----
                "v_fma_f32 %[sx], %[cDT2], %[k1x], %[X]\n\t"
                "v_fma_f32 %[sy], %[cDT2], %[k1y], %[Y]\n\t"
                "v_fma_f32 %[sz], %[cDT2], %[k1z], %[Z]\n\t"
                // ---- k2 = f(a) ----
                "v_sub_f32 %[t0], %[sy], %[sx]\n\t"
                "v_mul_f32 %[k2x], %[cS], %[t0]\n\t"
                "v_sub_f32 %[t1], %[cR], %[sz]\n\t"
                "v_fma_f32 %[k2y], %[sx], %[t1], -%[sy]\n\t"
                "v_mul_f32 %[t2], %[cB], %[sz]\n\t"
                "v_fma_f32 %[k2z], %[sx], %[sy], -%[t2]\n\t"
                // ---- stage b = x + DT/2*k2 ----
                "v_fma_f32 %[sx], %[cDT2], %[k2x], %[X]\n\t"
                "v_fma_f32 %[sy], %[cDT2], %[k2y], %[Y]\n\t"
                "v_fma_f32 %[sz], %[cDT2], %[k2z], %[Z]\n\t"
                // ---- k3 = f(b) ----
                "v_sub_f32 %[t0], %[sy], %[sx]\n\t"
                "v_mul_f32 %[k3x], %[cS], %[t0]\n\t"
                "v_sub_f32 %[t1], %[cR], %[sz]\n\t"
                "v_fma_f32 %[k3y], %[sx], %[t1], -%[sy]\n\t"
                "v_mul_f32 %[t2], %[cB], %[sz]\n\t"
                "v_fma_f32 %[k3z], %[sx], %[sy], -%[t2]\n\t"
                // ---- stage c = x + DT*k2   (sic: k2 — reference quirk) ----
                "v_fma_f32 %[sx], %[cDT], %[k2x], %[X]\n\t"
                "v_fma_f32 %[sy], %[cDT], %[k2y], %[Y]\n\t"
                "v_fma_f32 %[sz], %[cDT], %[k2z], %[Z]\n\t"
                // ---- k4 = f(c) ----
                "v_sub_f32 %[t0], %[sy], %[sx]\n\t"
                "v_mul_f32 %[k4x], %[cS], %[t0]\n\t"
                "v_sub_f32 %[t1], %[cR], %[sz]\n\t"
                "v_fma_f32 %[k4y], %[sx], %[t1], -%[sy]\n\t"
                "v_mul_f32 %[t2], %[cB], %[sz]\n\t"
                "v_fma_f32 %[k4z], %[sx], %[sy], -%[t2]\n\t"
                // ---- x += DT*(k1 + 2k2 + 2k3 + k4)/6  (R9 tree) ----
                "v_fma_f32 %[t0], 2.0, %[k2x], %[k1x]\n\t"
                "v_fma_f32 %[t0], 2.0, %[k3x], %[t0]\n\t"
                "v_add_f32 %[t0], %[t0], %[k4x]\n\t"
                "v_mul_f32 %[t0], %[cDT], %[t0]\n\t"
                "v_fma_f32 %[X], %[t0], %[c6], %[X]\n\t"
                "v_fma_f32 %[t1], 2.0, %[k2y], %[k1y]\n\t"
                "v_fma_f32 %[t1], 2.0, %[k3y], %[t1]\n\t"
                "v_add_f32 %[t1], %[t1], %[k4y]\n\t"
                "v_mul_f32 %[t1], %[cDT], %[t1]\n\t"
                "v_fma_f32 %[Y], %[t1], %[c6], %[Y]\n\t"
                "v_fma_f32 %[t2], 2.0, %[k2z], %[k1z]\n\t"
                "v_fma_f32 %[t2], 2.0, %[k3z], %[t2]\n\t"
                "v_add_f32 %[t2], %[t2], %[k4z]\n\t"
                "v_mul_f32 %[t2], %[cDT], %[t2]\n\t"
                "v_fma_f32 %[Z], %[t2], %[c6], %[Z]\n\t"
                // ---- J entries into dead k regs ----
                "v_sub_f32 %[t0], %[cR], %[Z]\n\t"
                "v_mul_f32 %[k1x], %[cDT], %[t0]\n\t"      // j10
                "v_mul_f32 %[k1y], -%[cDT], %[X]\n\t"      // j12 (neg mod == cNDT*X)
                "v_mul_f32 %[k1z], %[cDT], %[Y]\n\t"       // j20
                "v_mul_f32 %[k2x], %[cDT], %[X]\n\t"       // j21
                // ---- Q = J @ Q, column-wise, results in-place ----
                // col 0
                "v_mul_f32 %[t0], %[cJ00], %[q00]\n\t"
                "v_mul_f32 %[t1], %[k1x], %[q00]\n\t"
                "v_mul_f32 %[t2], %[k1z], %[q00]\n\t"
                "v_fma_f32 %[q00], %[cJ01], %[q10], %[t0]\n\t"
                "v_fma_f32 %[t1], %[cJ11], %[q10], %[t1]\n\t"
                "v_fma_f32 %[t2], %[k2x], %[q10], %[t2]\n\t"
                "v_fma_f32 %[q10], %[k1y], %[q20], %[t1]\n\t"
                "v_fma_f32 %[q20], %[cJ22], %[q20], %[t2]\n\t"
                // col 1
                "v_mul_f32 %[t0], %[cJ00], %[q01]\n\t"
                "v_mul_f32 %[t1], %[k1x], %[q01]\n\t"
                "v_mul_f32 %[t2], %[k1z], %[q01]\n\t"
                "v_fma_f32 %[q01], %[cJ01], %[q11], %[t0]\n\t"
                "v_fma_f32 %[t1], %[cJ11], %[q11], %[t1]\n\t"
                "v_fma_f32 %[t2], %[k2x], %[q11], %[t2]\n\t"
                "v_fma_f32 %[q11], %[k1y], %[q21], %[t1]\n\t"
                "v_fma_f32 %[q21], %[cJ22], %[q21], %[t2]\n\t"
                // col 2
                "v_mul_f32 %[t0], %[cJ00], %[q02]\n\t"
                "v_mul_f32 %[t1], %[k1x], %[q02]\n\t"
                "v_mul_f32 %[t2], %[k1z], %[q02]\n\t"
                "v_fma_f32 %[q02], %[cJ01], %[q12], %[t0]\n\t"
                "v_fma_f32 %[t1], %[cJ11], %[q12], %[t1]\n\t"
                "v_fma_f32 %[t2], %[k2x], %[q12], %[t2]\n\t"
                "v_fma_f32 %[q12], %[k1y], %[q22], %[t1]\n\t"
                "v_fma_f32 %[q22], %[cJ22], %[q22], %[t2]"
                : [X] "+v"(X), [Y] "+v"(Y), [Z] "+v"(Z),
                  [q00] "+v"(q00), [q01] "+v"(q01), [q02] "+v"(q02),
                  [q10] "+v"(q10), [q11] "+v"(q11), [q12] "+v"(q12),
                  [q20] "+v"(q20), [q21] "+v"(q21), [q22] "+v"(q22),
                  [t0] "=&v"(t0), [t1] "=&v"(t1), [t2] "=&v"(t2),
                  [sx] "=&v"(sx), [sy] "=&v"(sy), [sz] "=&v"(sz),
                  [k1x] "=&v"(k1x), [k1y] "=&v"(k1y), [k1z] "=&v"(k1z),
                  [k2x] "=&v"(k2x), [k2y] "=&v"(k2y), [k2z] "=&v"(k2z),
                  [k3x] "=&v"(k3x), [k3y] "=&v"(k3y), [k3z] "=&v"(k3z),
                  [k4x] "=&v"(k4x), [k4y] "=&v"(k4y), [k4z] "=&v"(k4z)
                : [cS] "v"(cS), [cR] "v"(cR), [cB] "v"(cB),
                  [cDT] "v"(cDT), [cDT2] "v"(cDT2), [c6] "v"(c6),
                  [cJ00] "v"(cJ00), [cJ01] "v"(cJ01),
                  [cJ11] "v"(cJ11), [cJ22] "v"(cJ22));
        }
        it += n;

        // ---- Classical GS, unnormalized (coeffs from ORIGINAL columns).
        // Runs 5x total — plain C, amortized to noise.
        {
            float ib0 = q00 * q00 + q10 * q10 + q20 * q20;
            float rib0 = __builtin_amdgcn_rcpf(ib0);
            float d01 = q00 * q01 + q10 * q11 + q20 * q21;
            float c1 = d01 * rib0;
            float b10 = q01 - c1 * q00;
            float b11 = q11 - c1 * q10;
            float b12 = q21 - c1 * q20;
            float d02 = q00 * q02 + q10 * q12 + q20 * q22;
            float c2 = d02 * rib0;
            float e0 = q02 - c2 * q00;
            float e1 = q12 - c2 * q10;
            float e2 = q22 - c2 * q20;
            float ib1 = b10 * b10 + b11 * b11 + b12 * b12;
            float d12 = b10 * q02 + b11 * q12 + b12 * q22;
            float c3 = d12 * __builtin_amdgcn_rcpf(ib1);
            q02 = e0 - c3 * b10;
            q12 = e1 - c3 * b11;
            q22 = e2 - c3 * b12;
            q01 = b10; q11 = b11; q21 = b12;
        }
    }

    // Final column norms^2; lya_j = 0.5*ln2*log2(ib_j) / (t_last + DT)
    float ib0 = q00 * q00 + q10 * q10 + q20 * q20;
    float ib1 = q01 * q01 + q11 * q11 + q21 * q21;
    float ib2 = q02 * q02 + q12 * q12 + q22 * q22;

    float scale = LN2_HALF * __builtin_amdgcn_rcpf(t_last + 0.01f);
    out[0 * B + b] = __builtin_amdgcn_logf(ib0) * scale;
    out[1 * B + b] = __builtin_amdgcn_logf(ib1) * scale;
    out[2 * B + b] = __builtin_amdgcn_logf(ib2) * scale;
    out[3 * B + b] = X;
    out[4 * B + b] = Y;
    out[5 * B + b] = Z;
}

extern "C" void kernel_launch(void* const* d_in, const int* in_sizes, int n_in,
                              void* d_out, int out_size, void* d_ws, size_t ws_size,
                              hipStream_t stream) {
    const float* x0 = (const float*)d_in[0];
    const float* ts = (const float*)d_in[1];
    float* out = (float*)d_out;
    int B = in_sizes[0] / 3;
    int T = in_sizes[1];
    int threads = 256;
    int blocks = (B + threads - 1) / threads;
    lorenz_lya_kernel<<<blocks, threads, 0, stream>>>(x0, ts, out, B, T);
}